// Round 4
// baseline (242.728 us; speedup 1.0000x reference)
//
#include <hip/hip_runtime.h>
#include <hip/hip_bf16.h>

typedef _Float16 f16;
typedef _Float16 f16x4 __attribute__((ext_vector_type(4)));
typedef _Float16 f16x8 __attribute__((ext_vector_type(8)));
typedef float f32x4 __attribute__((ext_vector_type(4)));

#define DIM 1024
#define SEQ 2048
#define NB 2
#define NH 16
#define DHEAD 64
#define KVB 128

// ---------------- RMS norm (f32) + cast to f16 ----------------
__global__ __launch_bounds__(256) void rms_cast_kernel(
    const float* __restrict__ x, const float* __restrict__ ctx,
    const float* __restrict__ gamma, f16* __restrict__ xn, f16* __restrict__ cn)
{
  int row = blockIdx.x;
  const float* src; f16* dst;
  if (row < NB * SEQ) { src = x + (size_t)row * DIM;              dst = xn + (size_t)row * DIM; }
  else                { src = ctx + (size_t)(row - NB*SEQ) * DIM; dst = cn + (size_t)(row - NB*SEQ) * DIM; }
  int t = threadIdx.x;
  float4 v = ((const float4*)src)[t];
  float ss = v.x*v.x + v.y*v.y + v.z*v.z + v.w*v.w;
  #pragma unroll
  for (int m = 1; m < 64; m <<= 1) ss += __shfl_xor(ss, m, 64);
  __shared__ float red[4];
  if ((t & 63) == 0) red[t >> 6] = ss;
  __syncthreads();
  float total = red[0] + red[1] + red[2] + red[3];
  float scale = 32.0f / fmaxf(sqrtf(total), 1e-12f);
  float4 gv = ((const float4*)gamma)[t];
  dst[4*t+0] = (f16)(v.x * scale * gv.x);
  dst[4*t+1] = (f16)(v.y * scale * gv.y);
  dst[4*t+2] = (f16)(v.z * scale * gv.z);
  dst[4*t+3] = (f16)(v.w * scale * gv.w);
}

// ---------------- weight transpose + cast: W[K=1024][N] -> Wt[N][1024] ----------------
__global__ __launch_bounds__(256) void transpose_cast_kernel(
    const float* __restrict__ W, f16* __restrict__ Wt, int N)
{
  __shared__ float tile[32][33];
  int n0 = blockIdx.x * 32, k0 = blockIdx.y * 32;
  int tx = threadIdx.x & 31, ty = threadIdx.x >> 5;
  #pragma unroll
  for (int i = 0; i < 32; i += 8)
    tile[ty + i][tx] = W[(size_t)(k0 + ty + i) * N + n0 + tx];
  __syncthreads();
  #pragma unroll
  for (int i = 0; i < 32; i += 8)
    Wt[(size_t)(n0 + ty + i) * 1024 + k0 + tx] = (f16)tile[tx][ty + i];
}

// ---------------- GEMM: C[M][N] = A[M][1024] * Bt[N][1024]^T ----------------
// MODE 0: q-proj (x SCALE*log2e -> [b,h,s,d])
// MODE 1: kv-proj (k -> [b,h,s,d]; v scaled by scores -> TRANSPOSED [b,h,d,s])
// MODE 2: out-proj (f32 -> d_out row-major)
template<int MODE>
__global__ __launch_bounds__(256) void gemm_kernel(
    const f16* __restrict__ A, const f16* __restrict__ Bt,
    const float* __restrict__ scores,
    f16* __restrict__ o16a, f16* __restrict__ o16b, float* __restrict__ o32)
{
  __shared__ f16 As[128][40];
  __shared__ f16 Bs[128][40];
  const int m0 = blockIdx.x * 128, n0 = blockIdx.y * 128;
  const int tid = threadIdx.x, lane = tid & 63, w = tid >> 6;
  const int wm = w >> 1, wn = w & 1;
  const int g = lane >> 4, c = lane & 15;
  const int srow = tid >> 1, skc = (tid & 1) * 16;

  const f16* pa = A  + (size_t)(m0 + srow) * 1024 + skc;
  const f16* pb = Bt + (size_t)(n0 + srow) * 1024 + skc;

  f32x4 acc[4][4] = {};

  float4 ra0 = ((const float4*)pa)[0], ra1 = ((const float4*)pa)[1];
  float4 rb0 = ((const float4*)pb)[0], rb1 = ((const float4*)pb)[1];

  for (int k0 = 0; k0 < 1024; k0 += 32) {
    __syncthreads();
    *(float4*)&As[srow][skc]     = ra0;
    *(float4*)&As[srow][skc + 8] = ra1;
    *(float4*)&Bs[srow][skc]     = rb0;
    *(float4*)&Bs[srow][skc + 8] = rb1;
    if (k0 + 32 < 1024) {
      const f16* qa = pa + k0 + 32; const f16* qb = pb + k0 + 32;
      ra0 = ((const float4*)qa)[0]; ra1 = ((const float4*)qa)[1];
      rb0 = ((const float4*)qb)[0]; rb1 = ((const float4*)qb)[1];
    }
    __syncthreads();
    f16x8 af[4], bf[4];
    #pragma unroll
    for (int tm = 0; tm < 4; tm++) af[tm] = *(const f16x8*)&As[wm*64 + tm*16 + c][g*8];
    #pragma unroll
    for (int tn = 0; tn < 4; tn++) bf[tn] = *(const f16x8*)&Bs[wn*64 + tn*16 + c][g*8];
    #pragma unroll
    for (int tm = 0; tm < 4; tm++)
      #pragma unroll
      for (int tn = 0; tn < 4; tn++)
        acc[tm][tn] = __builtin_amdgcn_mfma_f32_16x16x32_f16(af[tm], bf[tn], acc[tm][tn], 0, 0, 0);
  }

  #pragma unroll
  for (int tm = 0; tm < 4; tm++) {
    #pragma unroll
    for (int tn = 0; tn < 4; tn++) {
      int rg0 = m0 + wm*64 + tm*16 + g*4;          // 4 consecutive global rows
      int cg  = n0 + wn*64 + tn*16 + c;
      int b = rg0 >> 11, s0 = rg0 & 2047;
      if (MODE == 0) {
        int h = cg >> 6, d = cg & 63;
        #pragma unroll
        for (int r = 0; r < 4; r++)
          o16a[(((size_t)(b*NH + h))*SEQ + s0 + r)*DHEAD + d] =
              (f16)(acc[tm][tn][r] * 0.18033688011112043f);  // SCALE*log2(e)
      } else if (MODE == 1) {
        int hh = (cg & 1023) >> 6, d = cg & 63;
        if (cg < 1024) {
          #pragma unroll
          for (int r = 0; r < 4; r++)
            o16a[(((size_t)(b*NH + hh))*SEQ + s0 + r)*DHEAD + d] = (f16)acc[tm][tn][r];
        } else {
          float4 sc = *(const float4*)(scores + b*SEQ + s0);
          f16x4 pk;
          pk[0] = (f16)(acc[tm][tn][0] * sc.x);
          pk[1] = (f16)(acc[tm][tn][1] * sc.y);
          pk[2] = (f16)(acc[tm][tn][2] * sc.z);
          pk[3] = (f16)(acc[tm][tn][3] * sc.w);
          *(f16x4*)(o16b + (((size_t)(b*NH + hh))*DHEAD + d)*SEQ + s0) = pk;
        }
      } else {
        #pragma unroll
        for (int r = 0; r < 4; r++)
          o32[(size_t)(rg0 + r) * 1024 + cg] = acc[tm][tn][r];
      }
    }
  }
}

// ---------------- flash attention: S^T = K Q^T, O^T = V^T P^T ----------------
// LDS arena (bytes):
//   Ks: [0,16384)        K tile [128 kv][128B], 16B-chunk XOR swizzle byte^=((row&7)<<4)
//   Vt: [16384,33792)    V^T tile [64 d][272B] (136 f16/row, 128 used, pad 16B-mult)
//   Pt: [33792,51200)    per-wave P^T as [q=16][272B] (kv contiguous)
//   epilogue bounce [64][144B] aliases Ks
#define KS_OFF 0
#define VT_OFF 16384
#define PT_OFF 33792

__global__ __launch_bounds__(256, 3) void attn_kernel(
    const f16* __restrict__ Q, const f16* __restrict__ K,
    const f16* __restrict__ Vt, f16* __restrict__ O)
{
  __shared__ __align__(16) char L[51200];

  const int bh = blockIdx.y;
  const int q0 = blockIdx.x * 64;
  const int tid = threadIdx.x, lane = tid & 63, w = tid >> 6;
  const int g = lane >> 4, c = lane & 15;

  const f16* Qb  = Q  + (size_t)bh * SEQ * DHEAD;
  const f16* Kb  = K  + (size_t)bh * SEQ * DHEAD;
  const f16* Vbt = Vt + (size_t)bh * DHEAD * SEQ;   // [d][kv]

  // Q fragments: lane's q = q0 + w*16 + c, d = g*8.. (+32)
  f16x8 aq[2];
  {
    int qr = q0 + w*16 + c;
    aq[0] = *(const f16x8*)(Qb + (size_t)qr * DHEAD + g*8);
    aq[1] = *(const f16x8*)(Qb + (size_t)qr * DHEAD + 32 + g*8);
  }

  f32x4 oacc[4] = {};          // O^T: lane holds O[q=c][d = dt*16 + 4g+r]
  float mr = -1e30f, lr = 0.f; // per-lane, q = c

  // K staging: 2 threads/row
  const int srow = tid >> 1, sh = tid & 1;
  const f16* kg = Kb + (size_t)srow * DHEAD + sh * 32;
  unsigned ksw[4];
  #pragma unroll
  for (int i = 0; i < 4; i++)
    ksw[i] = KS_OFF + srow*128 + ((sh*64 + i*16) ^ ((srow & 7) << 4));

  // V^T staging: thread owns d-row tid>>2, 32-elem chunk (tid&3)
  const int vd = tid >> 2, vch = tid & 3;
  const f16* vg = Vbt + (size_t)vd * SEQ + vch * 32;
  const unsigned vsw = VT_OFF + vd*272 + vch*64;

  // fragment bases
  const unsigned sl0   = ((g ^ (c & 7)) << 4);          // Ks chunk, kc=0 (kc=1: ^0x40)
  const unsigned ks_rd = KS_OFF + c*128;                // + ct*2048
  const unsigned vt_rd = VT_OFF + c*272 + g*16;         // + dt*4352 + kc*64
  const unsigned pt_wc = PT_OFF + w*4352 + c*272;       // write: + ct*32 + g*8 ; read: + kc*64 + g*16

  float4 kr[4], vr[4];
  {
    const float4* p  = (const float4*)kg;
    kr[0]=p[0]; kr[1]=p[1]; kr[2]=p[2]; kr[3]=p[3];
    const float4* q2 = (const float4*)vg;
    vr[0]=q2[0]; vr[1]=q2[1]; vr[2]=q2[2]; vr[3]=q2[3];
  }

  for (int kv0 = 0; kv0 < SEQ; kv0 += KVB) {
    __syncthreads();
    #pragma unroll
    for (int i = 0; i < 4; i++) *(float4*)(L + ksw[i]) = kr[i];
    #pragma unroll
    for (int i = 0; i < 4; i++) *(float4*)(L + vsw + i*16) = vr[i];
    __syncthreads();

    if (kv0 + KVB < SEQ) {   // prefetch next tile under compute
      const float4* p  = (const float4*)(kg + (size_t)(kv0 + KVB) * DHEAD);
      kr[0]=p[0]; kr[1]=p[1]; kr[2]=p[2]; kr[3]=p[3];
      const float4* q2 = (const float4*)(vg + kv0 + KVB);
      vr[0]=q2[0]; vr[1]=q2[1]; vr[2]=q2[2]; vr[3]=q2[3];
    }

    // ---- S^T = K * Q^T : s[ct] rows kv = ct*16+4g+r, col q = c ----
    f32x4 s[8];
    #pragma unroll
    for (int ct = 0; ct < 8; ct++) {
      f16x8 k0 = *(const f16x8*)(L + ks_rd + ct*2048 + sl0);
      f16x8 k1 = *(const f16x8*)(L + ks_rd + ct*2048 + (sl0 ^ 0x40));
      f32x4 z = {0.f, 0.f, 0.f, 0.f};
      z     = __builtin_amdgcn_mfma_f32_16x16x32_f16(k0, aq[0], z, 0, 0, 0);
      s[ct] = __builtin_amdgcn_mfma_f32_16x16x32_f16(k1, aq[1], z, 0, 0, 0);
    }

    // ---- online softmax, per-lane (q = c), exp2 domain ----
    float mx = -1e30f;
    #pragma unroll
    for (int ct = 0; ct < 8; ct++)
      mx = fmaxf(mx, fmaxf(fmaxf(s[ct][0], s[ct][1]), fmaxf(s[ct][2], s[ct][3])));
    mx = fmaxf(mx, __shfl_xor(mx, 16, 64));
    mx = fmaxf(mx, __shfl_xor(mx, 32, 64));
    float mn = fmaxf(mr, mx);
    float al = __builtin_amdgcn_exp2f(mr - mn);
    mr = mn;
    float rs = 0.f;
    #pragma unroll
    for (int ct = 0; ct < 8; ct++) {
      #pragma unroll
      for (int r = 0; r < 4; r++) {
        float p = __builtin_amdgcn_exp2f(s[ct][r] - mn);
        s[ct][r] = p; rs += p;
      }
    }
    rs += __shfl_xor(rs, 16, 64);
    rs += __shfl_xor(rs, 32, 64);
    lr = lr * al + rs;
    #pragma unroll
    for (int dt = 0; dt < 4; dt++)
      #pragma unroll
      for (int r = 0; r < 4; r++) oacc[dt][r] *= al;

    // ---- P^T -> wave-private LDS: Pt[q=c][kv], kv contiguous per write ----
    #pragma unroll
    for (int ct = 0; ct < 8; ct++) {
      f16x4 pk;
      pk[0] = (f16)s[ct][0]; pk[1] = (f16)s[ct][1];
      pk[2] = (f16)s[ct][2]; pk[3] = (f16)s[ct][3];
      *(f16x4*)(L + pt_wc + ct*32 + g*8) = pk;
    }

    // ---- O^T += V^T * P^T ----
    #pragma unroll
    for (int kc = 0; kc < 4; kc++) {
      f16x8 bp = *(const f16x8*)(L + pt_wc + kc*64 + g*16);
      #pragma unroll
      for (int dt = 0; dt < 4; dt++) {
        f16x8 av = *(const f16x8*)(L + vt_rd + dt*4352 + kc*64);
        oacc[dt] = __builtin_amdgcn_mfma_f32_16x16x32_f16(av, bp, oacc[dt], 0, 0, 0);
      }
    }
  }

  // ---- epilogue: O^T -> LDS bounce -> coalesced global ----
  __syncthreads();
  {
    float inv = 1.0f / lr;
    #pragma unroll
    for (int dt = 0; dt < 4; dt++) {
      f16x4 pk;
      pk[0] = (f16)(oacc[dt][0] * inv);
      pk[1] = (f16)(oacc[dt][1] * inv);
      pk[2] = (f16)(oacc[dt][2] * inv);
      pk[3] = (f16)(oacc[dt][3] * inv);
      *(f16x4*)(L + (16*w + c)*144 + (dt*16 + 4*g)*2) = pk;
    }
  }
  __syncthreads();
  {
    const int b = bh >> 4, h = bh & 15;
    int qr = tid >> 2, ch = tid & 3;
    float4 a0 = *(const float4*)(L + qr*144 + ch*32);
    float4 a1 = *(const float4*)(L + qr*144 + ch*32 + 16);
    f16* dst = O + ((size_t)(b*SEQ + q0 + qr))*1024 + h*64 + ch*16;
    *(float4*)dst = a0;
    *(float4*)(dst + 8) = a1;
  }
}

extern "C" void kernel_launch(void* const* d_in, const int* in_sizes, int n_in,
                              void* d_out, int out_size, void* d_ws, size_t ws_size,
                              hipStream_t stream)
{
  const float* x      = (const float*)d_in[0];
  const float* ctx    = (const float*)d_in[1];
  const float* scores = (const float*)d_in[2];
  const float* gamma  = (const float*)d_in[4];
  const float* Wq     = (const float*)d_in[5];
  const float* Wkv    = (const float*)d_in[6];
  const float* Wout   = (const float*)d_in[7];
  float* out = (float*)d_out;

  char* ws = (char*)d_ws;
  const size_t MB = 1024 * 1024;
  f16* xn   = (f16*)(ws);
  f16* cn   = (f16*)(ws + 8*MB);
  f16* WqT  = (f16*)(ws + 16*MB);
  f16* WkvT = (f16*)(ws + 18*MB);
  f16* WoT  = (f16*)(ws + 22*MB);
  f16* qb   = (f16*)(ws + 24*MB);
  f16* kb   = (f16*)(ws + 32*MB);
  f16* vbT  = (f16*)(ws + 40*MB);   // [b*h][d][kv]
  f16* ao   = xn;

  rms_cast_kernel<<<NB*SEQ*2, 256, 0, stream>>>(x, ctx, gamma, xn, cn);
  transpose_cast_kernel<<<dim3(32, 32), 256, 0, stream>>>(Wq,  WqT,  1024);
  transpose_cast_kernel<<<dim3(64, 32), 256, 0, stream>>>(Wkv, WkvT, 2048);
  transpose_cast_kernel<<<dim3(32, 32), 256, 0, stream>>>(Wout, WoT, 1024);
  gemm_kernel<0><<<dim3(32, 8),  256, 0, stream>>>(xn, WqT,  nullptr, qb, nullptr, nullptr);
  gemm_kernel<1><<<dim3(32, 16), 256, 0, stream>>>(cn, WkvT, scores,  kb, vbT,     nullptr);
  attn_kernel<<<dim3(SEQ/64, NB*NH), 256, 0, stream>>>(qb, kb, vbT, ao);
  gemm_kernel<2><<<dim3(32, 8),  256, 0, stream>>>(ao, WoT,  nullptr, nullptr, nullptr, out);
}

// Round 5
// 147.541 us; speedup vs baseline: 1.6452x; 1.6452x over previous
//
#include <hip/hip_runtime.h>
#include <hip/hip_bf16.h>

typedef _Float16 f16;
typedef _Float16 f16x4 __attribute__((ext_vector_type(4)));
typedef _Float16 f16x8 __attribute__((ext_vector_type(8)));
typedef float f32x4 __attribute__((ext_vector_type(4)));

#define DIM 1024
#define SEQ 2048
#define NB 2
#define NH 16
#define DHEAD 64
#define KVB 64
#define QBLK 256

// ---------------- RMS norm (f32) + cast to f16 ----------------
__global__ __launch_bounds__(256) void rms_cast_kernel(
    const float* __restrict__ x, const float* __restrict__ ctx,
    const float* __restrict__ gamma, f16* __restrict__ xn, f16* __restrict__ cn)
{
  int row = blockIdx.x;
  const float* src; f16* dst;
  if (row < NB * SEQ) { src = x + (size_t)row * DIM;              dst = xn + (size_t)row * DIM; }
  else                { src = ctx + (size_t)(row - NB*SEQ) * DIM; dst = cn + (size_t)(row - NB*SEQ) * DIM; }
  int t = threadIdx.x;
  float4 v = ((const float4*)src)[t];
  float ss = v.x*v.x + v.y*v.y + v.z*v.z + v.w*v.w;
  #pragma unroll
  for (int m = 1; m < 64; m <<= 1) ss += __shfl_xor(ss, m, 64);
  __shared__ float red[4];
  if ((t & 63) == 0) red[t >> 6] = ss;
  __syncthreads();
  float total = red[0] + red[1] + red[2] + red[3];
  float scale = 32.0f / fmaxf(sqrtf(total), 1e-12f);
  float4 gv = ((const float4*)gamma)[t];
  dst[4*t+0] = (f16)(v.x * scale * gv.x);
  dst[4*t+1] = (f16)(v.y * scale * gv.y);
  dst[4*t+2] = (f16)(v.z * scale * gv.z);
  dst[4*t+3] = (f16)(v.w * scale * gv.w);
}

// ---------------- fused weight transpose + cast (all 3 weights, one launch) ----------------
__global__ __launch_bounds__(256) void transpose_cast3_kernel(
    const float* __restrict__ Wq, const float* __restrict__ Wkv, const float* __restrict__ Wout,
    f16* __restrict__ WqT, f16* __restrict__ WkvT, f16* __restrict__ WoT)
{
  __shared__ float tile[32][33];
  int bx = blockIdx.x;
  const float* W; f16* Wt; int N, n0;
  if (bx < 32)      { W = Wq;   Wt = WqT;  N = 1024; n0 = bx * 32; }
  else if (bx < 96) { W = Wkv;  Wt = WkvT; N = 2048; n0 = (bx - 32) * 32; }
  else              { W = Wout; Wt = WoT;  N = 1024; n0 = (bx - 96) * 32; }
  int k0 = blockIdx.y * 32;
  int tx = threadIdx.x & 31, ty = threadIdx.x >> 5;
  #pragma unroll
  for (int i = 0; i < 32; i += 8)
    tile[ty + i][tx] = W[(size_t)(k0 + ty + i) * N + n0 + tx];
  __syncthreads();
  #pragma unroll
  for (int i = 0; i < 32; i += 8)
    Wt[(size_t)(n0 + ty + i) * 1024 + k0 + tx] = (f16)tile[tx][ty + i];
}

// ---------------- GEMM: C[M][N] = A[M][1024] * Bt[N][1024]^T ----------------
// MODE 0: q-proj (x SCALE*log2e -> [b,h,s,d])
// MODE 1: kv-proj (k -> [b,h,s,d]; v scaled by scores -> TRANSPOSED [b,h,d,s])
// MODE 2: out-proj (f32 -> d_out row-major)
template<int MODE>
__global__ __launch_bounds__(256) void gemm_kernel(
    const f16* __restrict__ A, const f16* __restrict__ Bt,
    const float* __restrict__ scores,
    f16* __restrict__ o16a, f16* __restrict__ o16b, float* __restrict__ o32)
{
  __shared__ f16 As[128][40];
  __shared__ f16 Bs[128][40];
  const int m0 = blockIdx.x * 128, n0 = blockIdx.y * 128;
  const int tid = threadIdx.x, lane = tid & 63, w = tid >> 6;
  const int wm = w >> 1, wn = w & 1;
  const int g = lane >> 4, c = lane & 15;
  const int srow = tid >> 1, skc = (tid & 1) * 16;

  const f16* pa = A  + (size_t)(m0 + srow) * 1024 + skc;
  const f16* pb = Bt + (size_t)(n0 + srow) * 1024 + skc;

  f32x4 acc[4][4] = {};

  float4 ra0 = ((const float4*)pa)[0], ra1 = ((const float4*)pa)[1];
  float4 rb0 = ((const float4*)pb)[0], rb1 = ((const float4*)pb)[1];

  for (int k0 = 0; k0 < 1024; k0 += 32) {
    __syncthreads();
    *(float4*)&As[srow][skc]     = ra0;
    *(float4*)&As[srow][skc + 8] = ra1;
    *(float4*)&Bs[srow][skc]     = rb0;
    *(float4*)&Bs[srow][skc + 8] = rb1;
    if (k0 + 32 < 1024) {
      const f16* qa = pa + k0 + 32; const f16* qb = pb + k0 + 32;
      ra0 = ((const float4*)qa)[0]; ra1 = ((const float4*)qa)[1];
      rb0 = ((const float4*)qb)[0]; rb1 = ((const float4*)qb)[1];
    }
    __syncthreads();
    f16x8 af[4], bf[4];
    #pragma unroll
    for (int tm = 0; tm < 4; tm++) af[tm] = *(const f16x8*)&As[wm*64 + tm*16 + c][g*8];
    #pragma unroll
    for (int tn = 0; tn < 4; tn++) bf[tn] = *(const f16x8*)&Bs[wn*64 + tn*16 + c][g*8];
    #pragma unroll
    for (int tm = 0; tm < 4; tm++)
      #pragma unroll
      for (int tn = 0; tn < 4; tn++)
        acc[tm][tn] = __builtin_amdgcn_mfma_f32_16x16x32_f16(af[tm], bf[tn], acc[tm][tn], 0, 0, 0);
  }

  #pragma unroll
  for (int tm = 0; tm < 4; tm++) {
    #pragma unroll
    for (int tn = 0; tn < 4; tn++) {
      int rg0 = m0 + wm*64 + tm*16 + g*4;          // 4 consecutive global rows
      int cg  = n0 + wn*64 + tn*16 + c;
      int b = rg0 >> 11, s0 = rg0 & 2047;
      if (MODE == 0) {
        int h = cg >> 6, d = cg & 63;
        #pragma unroll
        for (int r = 0; r < 4; r++)
          o16a[(((size_t)(b*NH + h))*SEQ + s0 + r)*DHEAD + d] =
              (f16)(acc[tm][tn][r] * 0.18033688011112043f);  // SCALE*log2(e)
      } else if (MODE == 1) {
        int hh = (cg & 1023) >> 6, d = cg & 63;
        if (cg < 1024) {
          #pragma unroll
          for (int r = 0; r < 4; r++)
            o16a[(((size_t)(b*NH + hh))*SEQ + s0 + r)*DHEAD + d] = (f16)acc[tm][tn][r];
        } else {
          float4 sc = *(const float4*)(scores + b*SEQ + s0);
          f16x4 pk;
          pk[0] = (f16)(acc[tm][tn][0] * sc.x);
          pk[1] = (f16)(acc[tm][tn][1] * sc.y);
          pk[2] = (f16)(acc[tm][tn][2] * sc.z);
          pk[3] = (f16)(acc[tm][tn][3] * sc.w);
          *(f16x4*)(o16b + (((size_t)(b*NH + hh))*DHEAD + d)*SEQ + s0) = pk;
        }
      } else {
        #pragma unroll
        for (int r = 0; r < 4; r++)
          o32[(size_t)(rg0 + r) * 1024 + cg] = acc[tm][tn][r];
      }
    }
  }
}

// ---------------- flash attention: 256 q-rows/block, 8 waves, KVB=64 ----------------
// S^T = K Q^T (swapped operands -> per-lane softmax), O^T = V^T P^T.
// LDS arena (bytes):
//   Ks: [0, 8192)        K tile [64 kv][128B], 16B-chunk XOR swizzle chunk^=(row&7)
//   Vt: [8192, 17408)    V^T tile [64 d][144B] (128B used)
//   Pt: [17408, 54272)   per-wave P^T [32 q][144B] (128B = 64 kv)  (also epilogue bounce)
#define KS_OFF 0
#define VT_OFF 8192
#define PT_OFF 17408

__global__ __launch_bounds__(512, 2) void attn_kernel(
    const f16* __restrict__ Q, const f16* __restrict__ K,
    const f16* __restrict__ Vt, f16* __restrict__ O)
{
  __shared__ __align__(16) char L[54272];

  const int bid = blockIdx.x;                      // 256 blocks, 1 per CU
  const int bh   = ((bid & 7) << 2) | ((bid >> 3) & 3);  // XCD-grouped heads
  const int q0   = (bid >> 5) * QBLK;
  const int tid = threadIdx.x, lane = tid & 63, w = tid >> 6;
  const int g = lane >> 4, c = lane & 15;

  const f16* Qb  = Q  + (size_t)bh * SEQ * DHEAD;
  const f16* Kb  = K  + (size_t)bh * SEQ * DHEAD;
  const f16* Vbt = Vt + (size_t)bh * DHEAD * SEQ;   // [d][kv]

  // Q fragments: wave owns 32 q rows (2 subtiles of 16); lane's q = q0+w*32+qs*16+c
  f16x8 aq[2][2];
  #pragma unroll
  for (int qs = 0; qs < 2; qs++) {
    int qr = q0 + w*32 + qs*16 + c;
    aq[qs][0] = *(const f16x8*)(Qb + (size_t)qr * DHEAD + g*8);
    aq[qs][1] = *(const f16x8*)(Qb + (size_t)qr * DHEAD + 32 + g*8);
  }

  f32x4 oacc[2][4] = {};            // O^T: oacc[qs][dt][r] = O[q=qs*16+c][d=dt*16+4g+r]
  float mr[2] = {-1e30f, -1e30f};
  float lr[2] = {0.f, 0.f};

  // staging: 512 threads; K row t>>3, chunk t&7 ; V^T d-row t>>3, kv-chunk t&7
  const int strow = tid >> 3, stch = tid & 7;
  const f16* kg = Kb  + (size_t)strow * DHEAD + stch * 8;
  const f16* vg = Vbt + (size_t)strow * SEQ   + stch * 8;
  const unsigned kswz = KS_OFF + strow*128 + ((stch ^ (strow & 7)) << 4);
  const unsigned vswz = VT_OFF + strow*144 + stch*16;
  const unsigned ptb  = PT_OFF + w*4608;

  float4 kr = *(const float4*)kg;
  float4 vr = *(const float4*)vg;

  for (int kv0 = 0; kv0 < SEQ; kv0 += KVB) {
    __syncthreads();
    *(float4*)(L + kswz) = kr;
    *(float4*)(L + vswz) = vr;
    __syncthreads();

    if (kv0 + KVB < SEQ) {   // prefetch next tile under compute
      kr = *(const float4*)(kg + (size_t)(kv0 + KVB) * DHEAD);
      vr = *(const float4*)(vg + kv0 + KVB);
    }

    // ---- S^T = K * Q^T : s[ct][qs] rows kv = ct*16+4g+r, col q = qs*16+c ----
    f32x4 s[4][2] = {};
    __builtin_amdgcn_s_setprio(1);
    #pragma unroll
    for (int ct = 0; ct < 4; ct++) {
      #pragma unroll
      for (int kc = 0; kc < 2; kc++) {
        f16x8 kf = *(const f16x8*)(L + KS_OFF + (ct*16 + c)*128 + (((kc*4 + g) ^ (c & 7)) << 4));
        s[ct][0] = __builtin_amdgcn_mfma_f32_16x16x32_f16(kf, aq[0][kc], s[ct][0], 0, 0, 0);
        s[ct][1] = __builtin_amdgcn_mfma_f32_16x16x32_f16(kf, aq[1][kc], s[ct][1], 0, 0, 0);
      }
    }
    __builtin_amdgcn_s_setprio(0);

    // ---- online softmax per q-subtile (per-lane; exp2 domain) ----
    #pragma unroll
    for (int qs = 0; qs < 2; qs++) {
      float mx = -1e30f;
      #pragma unroll
      for (int ct = 0; ct < 4; ct++)
        mx = fmaxf(mx, fmaxf(fmaxf(s[ct][qs][0], s[ct][qs][1]), fmaxf(s[ct][qs][2], s[ct][qs][3])));
      mx = fmaxf(mx, __shfl_xor(mx, 16, 64));
      mx = fmaxf(mx, __shfl_xor(mx, 32, 64));
      float mn = fmaxf(mr[qs], mx);
      float al = __builtin_amdgcn_exp2f(mr[qs] - mn);
      mr[qs] = mn;
      float rs = 0.f;
      #pragma unroll
      for (int ct = 0; ct < 4; ct++) {
        #pragma unroll
        for (int r = 0; r < 4; r++) {
          float p = __builtin_amdgcn_exp2f(s[ct][qs][r] - mn);
          s[ct][qs][r] = p; rs += p;
        }
      }
      rs += __shfl_xor(rs, 16, 64);
      rs += __shfl_xor(rs, 32, 64);
      lr[qs] = lr[qs] * al + rs;
      #pragma unroll
      for (int dt = 0; dt < 4; dt++)
        #pragma unroll
        for (int r = 0; r < 4; r++) oacc[qs][dt][r] *= al;

      // P^T -> wave-private LDS: Pt[q = qs*16+c][kv], 4 kv contiguous per write
      #pragma unroll
      for (int ct = 0; ct < 4; ct++) {
        f16x4 pk;
        pk[0] = (f16)s[ct][qs][0]; pk[1] = (f16)s[ct][qs][1];
        pk[2] = (f16)s[ct][qs][2]; pk[3] = (f16)s[ct][qs][3];
        *(f16x4*)(L + ptb + (qs*16 + c)*144 + ct*32 + g*8) = pk;
      }
    }

    // ---- O^T += V^T * P^T  (V-frag read once, reused across both q-subtiles) ----
    __builtin_amdgcn_s_setprio(1);
    #pragma unroll
    for (int kc = 0; kc < 2; kc++) {
      f16x8 bp0 = *(const f16x8*)(L + ptb + c*144        + kc*64 + g*16);
      f16x8 bp1 = *(const f16x8*)(L + ptb + (16 + c)*144 + kc*64 + g*16);
      #pragma unroll
      for (int dt = 0; dt < 4; dt++) {
        f16x8 vf = *(const f16x8*)(L + VT_OFF + (dt*16 + c)*144 + kc*64 + g*16);
        oacc[0][dt] = __builtin_amdgcn_mfma_f32_16x16x32_f16(vf, bp0, oacc[0][dt], 0, 0, 0);
        oacc[1][dt] = __builtin_amdgcn_mfma_f32_16x16x32_f16(vf, bp1, oacc[1][dt], 0, 0, 0);
      }
    }
    __builtin_amdgcn_s_setprio(0);
  }

  // ---- epilogue: normalize, bounce via wave-private Pt area, coalesced store ----
  #pragma unroll
  for (int qs = 0; qs < 2; qs++) {
    float inv = 1.0f / lr[qs];
    #pragma unroll
    for (int dt = 0; dt < 4; dt++) {
      f16x4 pk;
      pk[0] = (f16)(oacc[qs][dt][0] * inv);
      pk[1] = (f16)(oacc[qs][dt][1] * inv);
      pk[2] = (f16)(oacc[qs][dt][2] * inv);
      pk[3] = (f16)(oacc[qs][dt][3] * inv);
      *(f16x4*)(L + ptb + (qs*16 + c)*144 + (dt*16 + 4*g)*2) = pk;
    }
  }
  {
    const int b = bh >> 4, h = bh & 15;
    #pragma unroll
    for (int p = 0; p < 2; p++) {
      int ql = p*16 + (lane >> 2), chq = lane & 3;
      const char* src = L + ptb + ql*144 + chq*32;
      float4 a0 = *(const float4*)src;
      float4 a1 = *(const float4*)(src + 16);
      f16* dst = O + ((size_t)(b*SEQ + q0 + w*32 + ql))*1024 + h*64 + chq*16;
      *(float4*)dst = a0;
      *(float4*)(dst + 8) = a1;
    }
  }
}

extern "C" void kernel_launch(void* const* d_in, const int* in_sizes, int n_in,
                              void* d_out, int out_size, void* d_ws, size_t ws_size,
                              hipStream_t stream)
{
  const float* x      = (const float*)d_in[0];
  const float* ctx    = (const float*)d_in[1];
  const float* scores = (const float*)d_in[2];
  const float* gamma  = (const float*)d_in[4];
  const float* Wq     = (const float*)d_in[5];
  const float* Wkv    = (const float*)d_in[6];
  const float* Wout   = (const float*)d_in[7];
  float* out = (float*)d_out;

  char* ws = (char*)d_ws;
  const size_t MB = 1024 * 1024;
  f16* xn   = (f16*)(ws);
  f16* cn   = (f16*)(ws + 8*MB);
  f16* WqT  = (f16*)(ws + 16*MB);
  f16* WkvT = (f16*)(ws + 18*MB);
  f16* WoT  = (f16*)(ws + 22*MB);
  f16* qb   = (f16*)(ws + 24*MB);
  f16* kb   = (f16*)(ws + 32*MB);
  f16* vbT  = (f16*)(ws + 40*MB);   // [b*h][d][kv]
  f16* ao   = xn;

  rms_cast_kernel<<<NB*SEQ*2, 256, 0, stream>>>(x, ctx, gamma, xn, cn);
  transpose_cast3_kernel<<<dim3(128, 32), 256, 0, stream>>>(Wq, Wkv, Wout, WqT, WkvT, WoT);
  gemm_kernel<0><<<dim3(32, 8),  256, 0, stream>>>(xn, WqT,  nullptr, qb, nullptr, nullptr);
  gemm_kernel<1><<<dim3(32, 16), 256, 0, stream>>>(cn, WkvT, scores,  kb, vbT,     nullptr);
  attn_kernel<<<dim3(256), 512, 0, stream>>>(qb, kb, vbT, ao);
  gemm_kernel<2><<<dim3(32, 8),  256, 0, stream>>>(ao, WoT,  nullptr, nullptr, nullptr, out);
}

// Round 6
// 144.960 us; speedup vs baseline: 1.6744x; 1.0178x over previous
//
#include <hip/hip_runtime.h>
#include <hip/hip_bf16.h>

typedef _Float16 f16;
typedef _Float16 f16x4 __attribute__((ext_vector_type(4)));
typedef _Float16 f16x8 __attribute__((ext_vector_type(8)));
typedef float f32x4 __attribute__((ext_vector_type(4)));

#define DIM 1024
#define SEQ 2048
#define NB 2
#define NH 16
#define DHEAD 64
#define KVB 64
#define QBLK 128

// async global->LDS, 16B per lane. LDS dest must be wave-uniform base (HW adds lane*16).
__device__ __forceinline__ void gl_lds16(const f16* g, f16* l) {
  __builtin_amdgcn_global_load_lds(
      (const __attribute__((address_space(1))) unsigned int*)(g),
      (__attribute__((address_space(3))) unsigned int*)(l), 16, 0, 0);
}

// ---------------- RMS norm (f32) + cast to f16 ----------------
__global__ __launch_bounds__(256) void rms_cast_kernel(
    const float* __restrict__ x, const float* __restrict__ ctx,
    const float* __restrict__ gamma, f16* __restrict__ xn, f16* __restrict__ cn)
{
  int row = blockIdx.x;
  const float* src; f16* dst;
  if (row < NB * SEQ) { src = x + (size_t)row * DIM;              dst = xn + (size_t)row * DIM; }
  else                { src = ctx + (size_t)(row - NB*SEQ) * DIM; dst = cn + (size_t)(row - NB*SEQ) * DIM; }
  int t = threadIdx.x;
  float4 v = ((const float4*)src)[t];
  float ss = v.x*v.x + v.y*v.y + v.z*v.z + v.w*v.w;
  #pragma unroll
  for (int m = 1; m < 64; m <<= 1) ss += __shfl_xor(ss, m, 64);
  __shared__ float red[4];
  if ((t & 63) == 0) red[t >> 6] = ss;
  __syncthreads();
  float total = red[0] + red[1] + red[2] + red[3];
  float scale = 32.0f / fmaxf(sqrtf(total), 1e-12f);
  float4 gv = ((const float4*)gamma)[t];
  dst[4*t+0] = (f16)(v.x * scale * gv.x);
  dst[4*t+1] = (f16)(v.y * scale * gv.y);
  dst[4*t+2] = (f16)(v.z * scale * gv.z);
  dst[4*t+3] = (f16)(v.w * scale * gv.w);
}

// ---------------- fused weight transpose + cast (all 3 weights) ----------------
__global__ __launch_bounds__(256) void transpose_cast3_kernel(
    const float* __restrict__ Wq, const float* __restrict__ Wkv, const float* __restrict__ Wout,
    f16* __restrict__ WqT, f16* __restrict__ WkvT, f16* __restrict__ WoT)
{
  __shared__ float tile[32][33];
  int bx = blockIdx.x;
  const float* W; f16* Wt; int N, n0;
  if (bx < 32)      { W = Wq;   Wt = WqT;  N = 1024; n0 = bx * 32; }
  else if (bx < 96) { W = Wkv;  Wt = WkvT; N = 2048; n0 = (bx - 32) * 32; }
  else              { W = Wout; Wt = WoT;  N = 1024; n0 = (bx - 96) * 32; }
  int k0 = blockIdx.y * 32;
  int tx = threadIdx.x & 31, ty = threadIdx.x >> 5;
  #pragma unroll
  for (int i = 0; i < 32; i += 8)
    tile[ty + i][tx] = W[(size_t)(k0 + ty + i) * N + n0 + tx];
  __syncthreads();
  #pragma unroll
  for (int i = 0; i < 32; i += 8)
    Wt[(size_t)(n0 + ty + i) * 1024 + k0 + tx] = (f16)tile[tx][ty + i];
}

// ---------------- GEMM: C[M][N] = A[M][1024] * Bt[N][1024]^T ----------------
// 128x64 tile, BK=32, 4 waves each 64x32 (4x2 of 16x16x32).
// global_load_lds staging: LDS linear [row][32], logical chunk l stored at
// physical p = l ^ (row&3); frag reads use the same XOR -> <=2-way conflicts.
template<int MODE>
__global__ __launch_bounds__(256, 4) void gemm_kernel(
    const f16* __restrict__ A, const f16* __restrict__ Bt,
    const float* __restrict__ scores,
    f16* __restrict__ o16a, f16* __restrict__ o16b, float* __restrict__ o32)
{
  __shared__ f16 As[128][32];
  __shared__ f16 Bs[64][32];
  const int m0 = blockIdx.x * 128, n0 = blockIdx.y * 64;
  const int tid = threadIdx.x, lane = tid & 63, w = tid >> 6;
  const int wm = w >> 1, wn = w & 1;
  const int g = lane >> 4, c = lane & 15;

  // staging (per wave-call): row = base + lane>>2, physical chunk p = lane&3,
  // global logical chunk l = p ^ (row&3)
  const int sr4 = lane >> 2, sp = lane & 3;
  const int lA0 = sp ^ ((w*32 + sr4) & 3);       // rows w*32 + sr4
  const int lA1 = sp ^ ((w*32 + 16 + sr4) & 3);  // rows w*32+16 + sr4
  const int lB  = sp ^ ((w*16 + sr4) & 3);       // rows w*16 + sr4
  const f16* gA0 = A  + (size_t)(m0 + w*32 +      sr4) * 1024 + lA0 * 8;
  const f16* gA1 = A  + (size_t)(m0 + w*32 + 16 + sr4) * 1024 + lA1 * 8;
  const f16* gB  = Bt + (size_t)(n0 + w*16 +      sr4) * 1024 + lB  * 8;
  f16* dA0 = &As[w*32][0];
  f16* dA1 = &As[w*32 + 16][0];
  f16* dB  = &Bs[w*16][0];

  f32x4 acc[4][2] = {};

  for (int k0 = 0; k0 < 1024; k0 += 32) {
    __syncthreads();
    gl_lds16(gA0 + k0, dA0);
    gl_lds16(gA1 + k0, dA1);
    gl_lds16(gB  + k0, dB);
    __syncthreads();   // compiler drains vmcnt before barrier -> LDS valid
    f16x8 af[4], bf[2];
    #pragma unroll
    for (int tm = 0; tm < 4; tm++) af[tm] = *(const f16x8*)&As[wm*64 + tm*16 + c][(g ^ (c & 3)) * 8];
    #pragma unroll
    for (int tn = 0; tn < 2; tn++) bf[tn] = *(const f16x8*)&Bs[wn*32 + tn*16 + c][(g ^ (c & 3)) * 8];
    #pragma unroll
    for (int tm = 0; tm < 4; tm++)
      #pragma unroll
      for (int tn = 0; tn < 2; tn++)
        acc[tm][tn] = __builtin_amdgcn_mfma_f32_16x16x32_f16(af[tm], bf[tn], acc[tm][tn], 0, 0, 0);
  }

  #pragma unroll
  for (int tm = 0; tm < 4; tm++) {
    #pragma unroll
    for (int tn = 0; tn < 2; tn++) {
      int rg0 = m0 + wm*64 + tm*16 + g*4;          // 4 consecutive global rows
      int cg  = n0 + wn*32 + tn*16 + c;
      int b = rg0 >> 11, s0 = rg0 & 2047;
      if (MODE == 0) {
        int h = cg >> 6, d = cg & 63;
        #pragma unroll
        for (int r = 0; r < 4; r++)
          o16a[(((size_t)(b*NH + h))*SEQ + s0 + r)*DHEAD + d] =
              (f16)(acc[tm][tn][r] * 0.18033688011112043f);  // SCALE*log2(e)
      } else if (MODE == 1) {
        int hh = (cg & 1023) >> 6, d = cg & 63;
        if (cg < 1024) {
          #pragma unroll
          for (int r = 0; r < 4; r++)
            o16a[(((size_t)(b*NH + hh))*SEQ + s0 + r)*DHEAD + d] = (f16)acc[tm][tn][r];
        } else {
          float4 sc = *(const float4*)(scores + b*SEQ + s0);
          f16x4 pk;
          pk[0] = (f16)(acc[tm][tn][0] * sc.x);
          pk[1] = (f16)(acc[tm][tn][1] * sc.y);
          pk[2] = (f16)(acc[tm][tn][2] * sc.z);
          pk[3] = (f16)(acc[tm][tn][3] * sc.w);
          *(f16x4*)(o16b + (((size_t)(b*NH + hh))*DHEAD + d)*SEQ + s0) = pk;
        }
      } else {
        #pragma unroll
        for (int r = 0; r < 4; r++)
          o32[(size_t)(rg0 + r) * 1024 + cg] = acc[tm][tn][r];
      }
    }
  }
}

// ---------------- flash attention: 128 q-rows/block, 4 waves (32q each), KVB=64 ----------------
// S^T = K Q^T (per-lane softmax), O^T = V^T P^T.
// LDS arena (bytes):
//   Ks: [0, 8192)        K tile [64 kv][128B], 16B-chunk XOR swizzle chunk^=(row&7)
//   Vt: [8192, 17408)    V^T tile [64 d][144B] (128B used)
//   Pt: [17408, 35840)   per-wave P^T [32 q][144B]  (also epilogue bounce)
#define KS_OFF 0
#define VT_OFF 8192
#define PT_OFF 17408

__global__ __launch_bounds__(256, 2) void attn_kernel(
    const f16* __restrict__ Q, const f16* __restrict__ K,
    const f16* __restrict__ Vt, f16* __restrict__ O)
{
  __shared__ __align__(16) char L[35840];

  const int bid = blockIdx.x;                        // 512 blocks, 2/CU
  const int xcd = bid & 7, i = bid >> 3;             // i in 0..63
  const int bh  = xcd*4 + (i >> 4);                  // 4 heads per XCD
  const int q0  = (i & 15) * QBLK;
  const int tid = threadIdx.x, lane = tid & 63, w = tid >> 6;
  const int g = lane >> 4, c = lane & 15;

  const f16* Qb  = Q  + (size_t)bh * SEQ * DHEAD;
  const f16* Kb  = K  + (size_t)bh * SEQ * DHEAD;
  const f16* Vbt = Vt + (size_t)bh * DHEAD * SEQ;    // [d][kv]

  // Q fragments: wave owns 32 q rows (2 subtiles); lane's q = q0+w*32+qs*16+c
  f16x8 aq[2][2];
  #pragma unroll
  for (int qs = 0; qs < 2; qs++) {
    int qr = q0 + w*32 + qs*16 + c;
    aq[qs][0] = *(const f16x8*)(Qb + (size_t)qr * DHEAD + g*8);
    aq[qs][1] = *(const f16x8*)(Qb + (size_t)qr * DHEAD + 32 + g*8);
  }

  f32x4 oacc[2][4] = {};            // O^T: oacc[qs][dt][r] = O[q=qs*16+c][d=dt*16+4g+r]
  float mr[2] = {-1e30f, -1e30f};
  float lr[2] = {0.f, 0.f};

  // staging: 256 threads, each 32B of K and 32B of V^T
  const int strow = tid >> 2;                  // 0..63
  const int c2a = (tid & 3) * 2;               // 16B chunk pair c2a, c2a+1
  const f16* kg = Kb  + (size_t)strow * DHEAD + c2a * 8;
  const f16* vg = Vbt + (size_t)strow * SEQ   + c2a * 8;
  const unsigned ksw0 = KS_OFF + strow*128 + ((c2a       ^ (strow & 7)) << 4);
  const unsigned ksw1 = KS_OFF + strow*128 + (((c2a + 1) ^ (strow & 7)) << 4);
  const unsigned vswz = VT_OFF + strow*144 + c2a*16;
  const unsigned ptb  = PT_OFF + w*4608;

  float4 kr0 = ((const float4*)kg)[0], kr1 = ((const float4*)kg)[1];
  float4 vr0 = ((const float4*)vg)[0], vr1 = ((const float4*)vg)[1];

  for (int kv0 = 0; kv0 < SEQ; kv0 += KVB) {
    __syncthreads();
    *(float4*)(L + ksw0) = kr0;
    *(float4*)(L + ksw1) = kr1;
    *(float4*)(L + vswz)      = vr0;
    *(float4*)(L + vswz + 16) = vr1;
    __syncthreads();

    if (kv0 + KVB < SEQ) {   // prefetch next tile under compute
      const float4* p  = (const float4*)(kg + (size_t)(kv0 + KVB) * DHEAD);
      kr0 = p[0]; kr1 = p[1];
      const float4* q2 = (const float4*)(vg + kv0 + KVB);
      vr0 = q2[0]; vr1 = q2[1];
    }

    // ---- S^T = K * Q^T : s[ct][qs] rows kv = ct*16+4g+r, col q = qs*16+c ----
    f32x4 s[4][2] = {};
    __builtin_amdgcn_s_setprio(1);
    #pragma unroll
    for (int ct = 0; ct < 4; ct++) {
      #pragma unroll
      for (int kc = 0; kc < 2; kc++) {
        f16x8 kf = *(const f16x8*)(L + KS_OFF + (ct*16 + c)*128 + (((kc*4 + g) ^ (c & 7)) << 4));
        s[ct][0] = __builtin_amdgcn_mfma_f32_16x16x32_f16(kf, aq[0][kc], s[ct][0], 0, 0, 0);
        s[ct][1] = __builtin_amdgcn_mfma_f32_16x16x32_f16(kf, aq[1][kc], s[ct][1], 0, 0, 0);
      }
    }
    __builtin_amdgcn_s_setprio(0);

    // ---- online softmax per q-subtile (per-lane; exp2 domain) ----
    #pragma unroll
    for (int qs = 0; qs < 2; qs++) {
      float mx = -1e30f;
      #pragma unroll
      for (int ct = 0; ct < 4; ct++)
        mx = fmaxf(mx, fmaxf(fmaxf(s[ct][qs][0], s[ct][qs][1]), fmaxf(s[ct][qs][2], s[ct][qs][3])));
      mx = fmaxf(mx, __shfl_xor(mx, 16, 64));
      mx = fmaxf(mx, __shfl_xor(mx, 32, 64));
      float mn = fmaxf(mr[qs], mx);
      float al = __builtin_amdgcn_exp2f(mr[qs] - mn);
      mr[qs] = mn;
      float rs = 0.f;
      #pragma unroll
      for (int ct = 0; ct < 4; ct++) {
        #pragma unroll
        for (int r = 0; r < 4; r++) {
          float p = __builtin_amdgcn_exp2f(s[ct][qs][r] - mn);
          s[ct][qs][r] = p; rs += p;
        }
      }
      rs += __shfl_xor(rs, 16, 64);
      rs += __shfl_xor(rs, 32, 64);
      lr[qs] = lr[qs] * al + rs;
      #pragma unroll
      for (int dt = 0; dt < 4; dt++)
        #pragma unroll
        for (int r = 0; r < 4; r++) oacc[qs][dt][r] *= al;

      // P^T -> wave-private LDS: Pt[q = qs*16+c][kv]
      #pragma unroll
      for (int ct = 0; ct < 4; ct++) {
        f16x4 pk;
        pk[0] = (f16)s[ct][qs][0]; pk[1] = (f16)s[ct][qs][1];
        pk[2] = (f16)s[ct][qs][2]; pk[3] = (f16)s[ct][qs][3];
        *(f16x4*)(L + ptb + (qs*16 + c)*144 + ct*32 + g*8) = pk;
      }
    }

    // ---- O^T += V^T * P^T  (V-frag read once, reused across both q-subtiles) ----
    __builtin_amdgcn_s_setprio(1);
    #pragma unroll
    for (int kc = 0; kc < 2; kc++) {
      f16x8 bp0 = *(const f16x8*)(L + ptb + c*144        + kc*64 + g*16);
      f16x8 bp1 = *(const f16x8*)(L + ptb + (16 + c)*144 + kc*64 + g*16);
      #pragma unroll
      for (int dt = 0; dt < 4; dt++) {
        f16x8 vf = *(const f16x8*)(L + VT_OFF + (dt*16 + c)*144 + kc*64 + g*16);
        oacc[0][dt] = __builtin_amdgcn_mfma_f32_16x16x32_f16(vf, bp0, oacc[0][dt], 0, 0, 0);
        oacc[1][dt] = __builtin_amdgcn_mfma_f32_16x16x32_f16(vf, bp1, oacc[1][dt], 0, 0, 0);
      }
    }
    __builtin_amdgcn_s_setprio(0);
  }

  // ---- epilogue: normalize, bounce via wave-private Pt area, coalesced store ----
  #pragma unroll
  for (int qs = 0; qs < 2; qs++) {
    float inv = 1.0f / lr[qs];
    #pragma unroll
    for (int dt = 0; dt < 4; dt++) {
      f16x4 pk;
      pk[0] = (f16)(oacc[qs][dt][0] * inv);
      pk[1] = (f16)(oacc[qs][dt][1] * inv);
      pk[2] = (f16)(oacc[qs][dt][2] * inv);
      pk[3] = (f16)(oacc[qs][dt][3] * inv);
      *(f16x4*)(L + ptb + (qs*16 + c)*144 + (dt*16 + 4*g)*2) = pk;
    }
  }
  {
    const int b = bh >> 4, h = bh & 15;
    #pragma unroll
    for (int p = 0; p < 2; p++) {
      int ql = p*16 + (lane >> 2), chq = lane & 3;
      const char* src = L + ptb + ql*144 + chq*32;
      float4 a0 = *(const float4*)src;
      float4 a1 = *(const float4*)(src + 16);
      f16* dst = O + ((size_t)(b*SEQ + q0 + w*32 + ql))*1024 + h*64 + chq*16;
      *(float4*)dst = a0;
      *(float4*)(dst + 8) = a1;
    }
  }
}

extern "C" void kernel_launch(void* const* d_in, const int* in_sizes, int n_in,
                              void* d_out, int out_size, void* d_ws, size_t ws_size,
                              hipStream_t stream)
{
  const float* x      = (const float*)d_in[0];
  const float* ctx    = (const float*)d_in[1];
  const float* scores = (const float*)d_in[2];
  const float* gamma  = (const float*)d_in[4];
  const float* Wq     = (const float*)d_in[5];
  const float* Wkv    = (const float*)d_in[6];
  const float* Wout   = (const float*)d_in[7];
  float* out = (float*)d_out;

  char* ws = (char*)d_ws;
  const size_t MB = 1024 * 1024;
  f16* xn   = (f16*)(ws);
  f16* cn   = (f16*)(ws + 8*MB);
  f16* WqT  = (f16*)(ws + 16*MB);
  f16* WkvT = (f16*)(ws + 18*MB);
  f16* WoT  = (f16*)(ws + 22*MB);
  f16* qb   = (f16*)(ws + 24*MB);
  f16* kb   = (f16*)(ws + 32*MB);
  f16* vbT  = (f16*)(ws + 40*MB);   // [b*h][d][kv]
  f16* ao   = xn;

  rms_cast_kernel<<<NB*SEQ*2, 256, 0, stream>>>(x, ctx, gamma, xn, cn);
  transpose_cast3_kernel<<<dim3(128, 32), 256, 0, stream>>>(Wq, Wkv, Wout, WqT, WkvT, WoT);
  gemm_kernel<0><<<dim3(32, 16), 256, 0, stream>>>(xn, WqT,  nullptr, qb, nullptr, nullptr);
  gemm_kernel<1><<<dim3(32, 32), 256, 0, stream>>>(cn, WkvT, scores,  kb, vbT,     nullptr);
  attn_kernel<<<dim3(512), 256, 0, stream>>>(qb, kb, vbT, ao);
  gemm_kernel<2><<<dim3(32, 16), 256, 0, stream>>>(ao, WoT,  nullptr, nullptr, nullptr, out);
}

// Round 7
// 138.481 us; speedup vs baseline: 1.7528x; 1.0468x over previous
//
#include <hip/hip_runtime.h>
#include <hip/hip_bf16.h>

typedef _Float16 f16;
typedef _Float16 f16x2 __attribute__((ext_vector_type(2)));
typedef _Float16 f16x4 __attribute__((ext_vector_type(4)));
typedef _Float16 f16x8 __attribute__((ext_vector_type(8)));
typedef __fp16 h16x2 __attribute__((ext_vector_type(2)));
typedef float f32x4 __attribute__((ext_vector_type(4)));

#define DIM 1024
#define SEQ 2048
#define NB 2
#define NH 16
#define DHEAD 64
#define KVB 64
#define QBLK 128
#define NT (SEQ / KVB)

// async global->LDS, 16B per lane. LDS dest = wave-uniform base (HW adds lane*16).
__device__ __forceinline__ void gl_lds16(const f16* g, f16* l) {
  __builtin_amdgcn_global_load_lds(
      (const __attribute__((address_space(1))) unsigned int*)(g),
      (__attribute__((address_space(3))) unsigned int*)(l), 16, 0, 0);
}

__device__ __forceinline__ f16x2 pkrtz(float a, float b) {
  h16x2 t = __builtin_amdgcn_cvt_pkrtz(a, b);
  return __builtin_bit_cast(f16x2, t);
}

// ---------------- RMS norm (f32) + cast to f16 ----------------
__global__ __launch_bounds__(256) void rms_cast_kernel(
    const float* __restrict__ x, const float* __restrict__ ctx,
    const float* __restrict__ gamma, f16* __restrict__ xn, f16* __restrict__ cn)
{
  int row = blockIdx.x;
  const float* src; f16* dst;
  if (row < NB * SEQ) { src = x + (size_t)row * DIM;              dst = xn + (size_t)row * DIM; }
  else                { src = ctx + (size_t)(row - NB*SEQ) * DIM; dst = cn + (size_t)(row - NB*SEQ) * DIM; }
  int t = threadIdx.x;
  float4 v = ((const float4*)src)[t];
  float ss = v.x*v.x + v.y*v.y + v.z*v.z + v.w*v.w;
  #pragma unroll
  for (int m = 1; m < 64; m <<= 1) ss += __shfl_xor(ss, m, 64);
  __shared__ float red[4];
  if ((t & 63) == 0) red[t >> 6] = ss;
  __syncthreads();
  float total = red[0] + red[1] + red[2] + red[3];
  float scale = 32.0f / fmaxf(sqrtf(total), 1e-12f);
  float4 gv = ((const float4*)gamma)[t];
  dst[4*t+0] = (f16)(v.x * scale * gv.x);
  dst[4*t+1] = (f16)(v.y * scale * gv.y);
  dst[4*t+2] = (f16)(v.z * scale * gv.z);
  dst[4*t+3] = (f16)(v.w * scale * gv.w);
}

// ---------------- fused weight transpose + cast (all 3 weights) ----------------
__global__ __launch_bounds__(256) void transpose_cast3_kernel(
    const float* __restrict__ Wq, const float* __restrict__ Wkv, const float* __restrict__ Wout,
    f16* __restrict__ WqT, f16* __restrict__ WkvT, f16* __restrict__ WoT)
{
  __shared__ float tile[32][33];
  int bx = blockIdx.x;
  const float* W; f16* Wt; int N, n0;
  if (bx < 32)      { W = Wq;   Wt = WqT;  N = 1024; n0 = bx * 32; }
  else if (bx < 96) { W = Wkv;  Wt = WkvT; N = 2048; n0 = (bx - 32) * 32; }
  else              { W = Wout; Wt = WoT;  N = 1024; n0 = (bx - 96) * 32; }
  int k0 = blockIdx.y * 32;
  int tx = threadIdx.x & 31, ty = threadIdx.x >> 5;
  #pragma unroll
  for (int i = 0; i < 32; i += 8)
    tile[ty + i][tx] = W[(size_t)(k0 + ty + i) * N + n0 + tx];
  __syncthreads();
  #pragma unroll
  for (int i = 0; i < 32; i += 8)
    Wt[(size_t)(n0 + ty + i) * 1024 + k0 + tx] = (f16)tile[tx][ty + i];
}

// ---------------- GEMM: C[M][N] = A[M][1024] * Bt[N][1024]^T ----------------
template<int MODE>
__global__ __launch_bounds__(256, 4) void gemm_kernel(
    const f16* __restrict__ A, const f16* __restrict__ Bt,
    const float* __restrict__ scores,
    f16* __restrict__ o16a, f16* __restrict__ o16b, float* __restrict__ o32)
{
  __shared__ f16 As[128][32];
  __shared__ f16 Bs[64][32];
  const int m0 = blockIdx.x * 128, n0 = blockIdx.y * 64;
  const int tid = threadIdx.x, lane = tid & 63, w = tid >> 6;
  const int wm = w >> 1, wn = w & 1;
  const int g = lane >> 4, c = lane & 15;

  const int sr4 = lane >> 2, sp = lane & 3;
  const int lA0 = sp ^ ((w*32 + sr4) & 3);
  const int lA1 = sp ^ ((w*32 + 16 + sr4) & 3);
  const int lB  = sp ^ ((w*16 + sr4) & 3);
  const f16* gA0 = A  + (size_t)(m0 + w*32 +      sr4) * 1024 + lA0 * 8;
  const f16* gA1 = A  + (size_t)(m0 + w*32 + 16 + sr4) * 1024 + lA1 * 8;
  const f16* gB  = Bt + (size_t)(n0 + w*16 +      sr4) * 1024 + lB  * 8;
  f16* dA0 = &As[w*32][0];
  f16* dA1 = &As[w*32 + 16][0];
  f16* dB  = &Bs[w*16][0];

  f32x4 acc[4][2] = {};

  for (int k0 = 0; k0 < 1024; k0 += 32) {
    __syncthreads();
    gl_lds16(gA0 + k0, dA0);
    gl_lds16(gA1 + k0, dA1);
    gl_lds16(gB  + k0, dB);
    __syncthreads();
    f16x8 af[4], bf[2];
    #pragma unroll
    for (int tm = 0; tm < 4; tm++) af[tm] = *(const f16x8*)&As[wm*64 + tm*16 + c][(g ^ (c & 3)) * 8];
    #pragma unroll
    for (int tn = 0; tn < 2; tn++) bf[tn] = *(const f16x8*)&Bs[wn*32 + tn*16 + c][(g ^ (c & 3)) * 8];
    #pragma unroll
    for (int tm = 0; tm < 4; tm++)
      #pragma unroll
      for (int tn = 0; tn < 2; tn++)
        acc[tm][tn] = __builtin_amdgcn_mfma_f32_16x16x32_f16(af[tm], bf[tn], acc[tm][tn], 0, 0, 0);
  }

  #pragma unroll
  for (int tm = 0; tm < 4; tm++) {
    #pragma unroll
    for (int tn = 0; tn < 2; tn++) {
      int rg0 = m0 + wm*64 + tm*16 + g*4;
      int cg  = n0 + wn*32 + tn*16 + c;
      int b = rg0 >> 11, s0 = rg0 & 2047;
      if (MODE == 0) {
        int h = cg >> 6, d = cg & 63;
        #pragma unroll
        for (int r = 0; r < 4; r++)
          o16a[(((size_t)(b*NH + h))*SEQ + s0 + r)*DHEAD + d] =
              (f16)(acc[tm][tn][r] * 0.18033688011112043f);  // SCALE*log2(e)
      } else if (MODE == 1) {
        int hh = (cg & 1023) >> 6, d = cg & 63;
        if (cg < 1024) {
          #pragma unroll
          for (int r = 0; r < 4; r++)
            o16a[(((size_t)(b*NH + hh))*SEQ + s0 + r)*DHEAD + d] = (f16)acc[tm][tn][r];
        } else {
          float4 sc = *(const float4*)(scores + b*SEQ + s0);
          f16x4 pk;
          pk[0] = (f16)(acc[tm][tn][0] * sc.x);
          pk[1] = (f16)(acc[tm][tn][1] * sc.y);
          pk[2] = (f16)(acc[tm][tn][2] * sc.z);
          pk[3] = (f16)(acc[tm][tn][3] * sc.w);
          *(f16x4*)(o16b + (((size_t)(b*NH + hh))*DHEAD + d)*SEQ + s0) = pk;
        }
      } else {
        #pragma unroll
        for (int r = 0; r < 4; r++)
          o32[(size_t)(rg0 + r) * 1024 + cg] = acc[tm][tn][r];
      }
    }
  }
}

// ---------------- flash attention: pipelined, gl_lds-staged, 3 LDS slots ----------------
// S^T = K Q^T (per-lane softmax), O^T = V^T P^T.
// Slot s (s=0,1,2) at s*16384: K [64 kv][128B] then V^T [64 d][128B], both with
// 16B-chunk XOR swizzle: physical chunk p = l ^ (row&7)  (l = logical chunk).
// Pt: [49152, 67584)  per-wave P^T [32 q][144B]  (also epilogue bounce)
#define PT_OFF 49152

__global__ __launch_bounds__(256, 2) void attn_kernel(
    const f16* __restrict__ Q, const f16* __restrict__ K,
    const f16* __restrict__ Vt, f16* __restrict__ O)
{
  __shared__ __align__(16) char L[67584];

  const int bid = blockIdx.x;                        // 512 blocks, 2/CU
  const int xcd = bid & 7, i = bid >> 3;
  const int bh  = xcd*4 + (i >> 4);                  // 4 heads per XCD
  const int q0  = (i & 15) * QBLK;
  const int tid = threadIdx.x, lane = tid & 63, w = tid >> 6;
  const int g = lane >> 4, c = lane & 15;

  const f16* Qb  = Q  + (size_t)bh * SEQ * DHEAD;
  const f16* Kb  = K  + (size_t)bh * SEQ * DHEAD;
  const f16* Vbt = Vt + (size_t)bh * DHEAD * SEQ;    // [d][kv]

  // Q fragments: wave owns 32 q rows (2 subtiles); lane's q = q0+w*32+qs*16+c
  f16x8 aq[2][2];
  #pragma unroll
  for (int qs = 0; qs < 2; qs++) {
    int qr = q0 + w*32 + qs*16 + c;
    aq[qs][0] = *(const f16x8*)(Qb + (size_t)qr * DHEAD + g*8);
    aq[qs][1] = *(const f16x8*)(Qb + (size_t)qr * DHEAD + 32 + g*8);
  }

  f32x4 oacc[2][4] = {};            // O^T: oacc[qs][dt][r] = O[q=qs*16+c][d=dt*16+4g+r]
  float mr[2] = {-1e30f, -1e30f};
  float lr[2] = {0.f, 0.f};

  // staging constants: wave writes 2x1KB of K + 2x1KB of V per stage
  const int sj = lane >> 3;                    // row within 1KB chunk (8 rows)
  const int sl = (lane & 7) ^ sj;              // pre-swizzled source chunk
  const f16* kgb0 = Kb  + (size_t)(w*16     + sj) * DHEAD + sl*8;
  const f16* kgb1 = Kb  + (size_t)(w*16 + 8 + sj) * DHEAD + sl*8;
  const f16* vgb0 = Vbt + (size_t)(w*16     + sj) * SEQ   + sl*8;
  const f16* vgb1 = Vbt + (size_t)(w*16 + 8 + sj) * SEQ   + sl*8;

  const unsigned ptb = PT_OFF + w*4608;
  const unsigned sw0 = ((g     ^ (c & 7)) << 4);   // kc=0 chunk swizzle
  const unsigned sw1 = (((4+g) ^ (c & 7)) << 4);   // kc=1

  unsigned sA = 0, sB = 16384, sC = 32768;

  f32x4 s[4][2];
  f16x4 pk[2][4];

#define STAGE(kv0v, slot) {                                                        \
    gl_lds16(kgb0 + (size_t)(kv0v)*DHEAD, (f16*)(L + (slot) + w*2048));            \
    gl_lds16(kgb1 + (size_t)(kv0v)*DHEAD, (f16*)(L + (slot) + w*2048 + 1024));     \
    gl_lds16(vgb0 + (kv0v),               (f16*)(L + (slot) + 8192 + w*2048));     \
    gl_lds16(vgb1 + (kv0v),               (f16*)(L + (slot) + 8192 + w*2048 + 1024)); }

#define QK_TILE(slot) {                                                            \
    _Pragma("unroll")                                                              \
    for (int ct = 0; ct < 4; ct++) {                                               \
      f16x8 k0 = *(const f16x8*)(L + (slot) + (ct*16 + c)*128 + sw0);              \
      f16x8 k1 = *(const f16x8*)(L + (slot) + (ct*16 + c)*128 + sw1);              \
      f32x4 z = {0.f, 0.f, 0.f, 0.f};                                              \
      s[ct][0] = __builtin_amdgcn_mfma_f32_16x16x32_f16(k0, aq[0][0], z, 0, 0, 0); \
      s[ct][0] = __builtin_amdgcn_mfma_f32_16x16x32_f16(k1, aq[0][1], s[ct][0], 0, 0, 0); \
      s[ct][1] = __builtin_amdgcn_mfma_f32_16x16x32_f16(k0, aq[1][0], z, 0, 0, 0); \
      s[ct][1] = __builtin_amdgcn_mfma_f32_16x16x32_f16(k1, aq[1][1], s[ct][1], 0, 0, 0); \
    } }

#define SOFTMAX() {                                                                \
    float mx0 = -1e30f, mx1 = -1e30f;                                              \
    _Pragma("unroll")                                                              \
    for (int ct = 0; ct < 4; ct++) {                                               \
      mx0 = fmaxf(mx0, fmaxf(fmaxf(s[ct][0][0], s[ct][0][1]), fmaxf(s[ct][0][2], s[ct][0][3]))); \
      mx1 = fmaxf(mx1, fmaxf(fmaxf(s[ct][1][0], s[ct][1][1]), fmaxf(s[ct][1][2], s[ct][1][3]))); \
    }                                                                              \
    mx0 = fmaxf(mx0, __shfl_xor(mx0, 16, 64)); mx0 = fmaxf(mx0, __shfl_xor(mx0, 32, 64)); \
    mx1 = fmaxf(mx1, __shfl_xor(mx1, 16, 64)); mx1 = fmaxf(mx1, __shfl_xor(mx1, 32, 64)); \
    if (!__all((mx0 <= mr[0] + 8.f) && (mx1 <= mr[1] + 8.f))) {                    \
      _Pragma("unroll")                                                            \
      for (int qs = 0; qs < 2; qs++) {                                             \
        float mxq = qs ? mx1 : mx0;                                                \
        float mn = fmaxf(mr[qs], mxq);                                             \
        float al = __builtin_amdgcn_exp2f(mr[qs] - mn);                            \
        mr[qs] = mn; lr[qs] *= al;                                                 \
        _Pragma("unroll")                                                          \
        for (int dt = 0; dt < 4; dt++)                                             \
          { oacc[qs][dt][0]*=al; oacc[qs][dt][1]*=al; oacc[qs][dt][2]*=al; oacc[qs][dt][3]*=al; } \
      }                                                                            \
    }                                                                              \
    _Pragma("unroll")                                                              \
    for (int qs = 0; qs < 2; qs++) {                                               \
      float rs = 0.f;                                                              \
      _Pragma("unroll")                                                            \
      for (int ct = 0; ct < 4; ct++) {                                             \
        float p0 = __builtin_amdgcn_exp2f(s[ct][qs][0] - mr[qs]);                  \
        float p1 = __builtin_amdgcn_exp2f(s[ct][qs][1] - mr[qs]);                  \
        float p2 = __builtin_amdgcn_exp2f(s[ct][qs][2] - mr[qs]);                  \
        float p3 = __builtin_amdgcn_exp2f(s[ct][qs][3] - mr[qs]);                  \
        rs += (p0 + p1) + (p2 + p3);                                               \
        f16x2 lo = pkrtz(p0, p1), hi = pkrtz(p2, p3);                              \
        pk[qs][ct] = __builtin_shufflevector(lo, hi, 0, 1, 2, 3);                  \
      }                                                                            \
      rs += __shfl_xor(rs, 16, 64); rs += __shfl_xor(rs, 32, 64);                  \
      lr[qs] += rs;                                                                \
    } }

#define PWRITE() {                                                                 \
    _Pragma("unroll")                                                              \
    for (int qs = 0; qs < 2; qs++)                                                 \
      _Pragma("unroll")                                                            \
      for (int ct = 0; ct < 4; ct++)                                               \
        *(f16x4*)(L + ptb + (qs*16 + c)*144 + ct*32 + g*8) = pk[qs][ct]; }

#define PV_TILE(slot) {                                                            \
    _Pragma("unroll")                                                              \
    for (int kc = 0; kc < 2; kc++) {                                               \
      f16x8 bp0 = *(const f16x8*)(L + ptb + c*144        + kc*64 + g*16);          \
      f16x8 bp1 = *(const f16x8*)(L + ptb + (16 + c)*144 + kc*64 + g*16);          \
      unsigned swc = kc ? sw1 : sw0;                                               \
      _Pragma("unroll")                                                            \
      for (int dt = 0; dt < 4; dt++) {                                             \
        f16x8 vf = *(const f16x8*)(L + (slot) + 8192 + (dt*16 + c)*128 + swc);     \
        oacc[0][dt] = __builtin_amdgcn_mfma_f32_16x16x32_f16(vf, bp0, oacc[0][dt], 0, 0, 0); \
        oacc[1][dt] = __builtin_amdgcn_mfma_f32_16x16x32_f16(vf, bp1, oacc[1][dt], 0, 0, 0); \
      }                                                                            \
    } }

  // ---- prologue: stage tiles 0,1; compute QK(0), softmax(0) ----
  STAGE(0, sA);
  STAGE(KVB, sB);
  __syncthreads();                    // drains vmcnt before barrier
  QK_TILE(sA);
  SOFTMAX();

  // ---- main loop: iter t does PV(t), QK(t+1), softmax(t+1), stage(t+2) ----
  for (int t = 0; t < NT - 1; ++t) {
    PWRITE();
    if (t < NT - 2) STAGE((t + 2) * KVB, sC);
    __builtin_amdgcn_s_setprio(1);
    QK_TILE(sB);
    PV_TILE(sA);
    __builtin_amdgcn_s_setprio(0);
    SOFTMAX();
    __syncthreads();
    unsigned tmp = sA; sA = sB; sB = sC; sC = tmp;
  }
  // ---- final tile ----
  PWRITE();
  PV_TILE(sA);

  // ---- epilogue: normalize, bounce via wave-private Pt area, coalesced store ----
  __syncthreads();
  #pragma unroll
  for (int qs = 0; qs < 2; qs++) {
    float inv = 1.0f / lr[qs];
    #pragma unroll
    for (int dt = 0; dt < 4; dt++) {
      f16x4 ov;
      ov[0] = (f16)(oacc[qs][dt][0] * inv);
      ov[1] = (f16)(oacc[qs][dt][1] * inv);
      ov[2] = (f16)(oacc[qs][dt][2] * inv);
      ov[3] = (f16)(oacc[qs][dt][3] * inv);
      *(f16x4*)(L + ptb + (qs*16 + c)*144 + (dt*16 + 4*g)*2) = ov;
    }
  }
  {
    const int b = bh >> 4, h = bh & 15;
    #pragma unroll
    for (int p = 0; p < 2; p++) {
      int ql = p*16 + (lane >> 2), chq = lane & 3;
      const char* src = L + ptb + ql*144 + chq*32;
      float4 a0 = *(const float4*)src;
      float4 a1 = *(const float4*)(src + 16);
      f16* dst = O + ((size_t)(b*SEQ + q0 + w*32 + ql))*1024 + h*64 + chq*16;
      *(float4*)dst = a0;
      *(float4*)(dst + 8) = a1;
    }
  }
#undef STAGE
#undef QK_TILE
#undef SOFTMAX
#undef PWRITE
#undef PV_TILE
}

extern "C" void kernel_launch(void* const* d_in, const int* in_sizes, int n_in,
                              void* d_out, int out_size, void* d_ws, size_t ws_size,
                              hipStream_t stream)
{
  const float* x      = (const float*)d_in[0];
  const float* ctx    = (const float*)d_in[1];
  const float* scores = (const float*)d_in[2];
  const float* gamma  = (const float*)d_in[4];
  const float* Wq     = (const float*)d_in[5];
  const float* Wkv    = (const float*)d_in[6];
  const float* Wout   = (const float*)d_in[7];
  float* out = (float*)d_out;

  char* ws = (char*)d_ws;
  const size_t MB = 1024 * 1024;
  f16* xn   = (f16*)(ws);
  f16* cn   = (f16*)(ws + 8*MB);
  f16* WqT  = (f16*)(ws + 16*MB);
  f16* WkvT = (f16*)(ws + 18*MB);
  f16* WoT  = (f16*)(ws + 22*MB);
  f16* qb   = (f16*)(ws + 24*MB);
  f16* kb   = (f16*)(ws + 32*MB);
  f16* vbT  = (f16*)(ws + 40*MB);   // [b*h][d][kv]
  f16* ao   = xn;

  rms_cast_kernel<<<NB*SEQ*2, 256, 0, stream>>>(x, ctx, gamma, xn, cn);
  transpose_cast3_kernel<<<dim3(128, 32), 256, 0, stream>>>(Wq, Wkv, Wout, WqT, WkvT, WoT);
  gemm_kernel<0><<<dim3(32, 16), 256, 0, stream>>>(xn, WqT,  nullptr, qb, nullptr, nullptr);
  gemm_kernel<1><<<dim3(32, 32), 256, 0, stream>>>(cn, WkvT, scores,  kb, vbT,     nullptr);
  attn_kernel<<<dim3(512), 256, 0, stream>>>(qb, kb, vbT, ao);
  gemm_kernel<2><<<dim3(32, 16), 256, 0, stream>>>(ao, WoT,  nullptr, nullptr, nullptr, out);
}